// Round 2
// baseline (256.973 us; speedup 1.0000x reference)
//
#include <hip/hip_runtime.h>
#include <hip/hip_bf16.h>
#include <cstdint>
#include <cstddef>

#define HD_B   4
#define SEQ    4096
#define CDIM   768
#define HEADS  12
#define HDIM   64
#define MROWS  (HD_B * SEQ)     // 16384
#define QSCALE 0.125f           // HEAD_DIM^-0.5
#define EPSV   1e-6f

typedef __attribute__((ext_vector_type(8))) short  short8v;  // 8 x bf16
typedef __attribute__((ext_vector_type(4))) float  f32x4;

__device__ __forceinline__ unsigned short f2b(float f) {
    unsigned int u = __float_as_uint(f);
    u += 0x7FFFu + ((u >> 16) & 1u);   // RNE
    return (unsigned short)(u >> 16);
}
__device__ __forceinline__ float b2f(unsigned short b) {
    return __uint_as_float(((unsigned int)b) << 16);
}
__device__ __forceinline__ float phi_f(float x) {  // elu(x)+1
    return x > 0.f ? x + 1.f : __expf(x);
}

#define GLOAD_LDS16(g, l)                                             \
    __builtin_amdgcn_global_load_lds(                                 \
        (__attribute__((address_space(1))) void*)(void*)(g),          \
        (__attribute__((address_space(3))) void*)(l), 16, 0, 0)

#define SBAR() do { __builtin_amdgcn_sched_barrier(0);                \
                    __builtin_amdgcn_s_barrier();                     \
                    __builtin_amdgcn_sched_barrier(0); } while (0)
#define VM4()  asm volatile("s_waitcnt vmcnt(4)" ::: "memory")
#define VM0()  asm volatile("s_waitcnt vmcnt(0)" ::: "memory")

// ---------------------------------------------------------------- converts
__global__ void cvt_f32_bf16(const float* __restrict__ in,
                             unsigned short* __restrict__ out, int n4) {
    int i = blockIdx.x * blockDim.x + threadIdx.x;
    if (i >= n4) return;
    float4 v = reinterpret_cast<const float4*>(in)[i];
    ushort4 o;
    o.x = f2b(v.x); o.y = f2b(v.y); o.z = f2b(v.z); o.w = f2b(v.w);
    reinterpret_cast<ushort4*>(out)[i] = o;
}

// ---------------------------------------------------------------- 8-phase 256^2 GEMM
// C[m,n] = sum_k A[m,k]*B[n,k], A: M x 768 bf16, B: N x 768 bf16 (B^T form).
// EPI 0: Q   -> bf16 out0, phi(QSCALE*(acc+bias0))
// EPI 1: KV  -> cols<768: bf16 out0 = phi(acc+bias0); cols>=768: bf16 out1 = acc+bias1
// EPI 2: P   -> fp32 out0 = acc+bias0
template<int Q>
__device__ __forceinline__ void mfma_quad(f32x4 (&acc)[8][4],
                                          const short8v (&a)[2][2],
                                          const short8v (&b)[4][2]) {
    __builtin_amdgcn_s_setprio(1);
#pragma unroll
    for (int mm = 0; mm < 2; ++mm)
#pragma unroll
        for (int n = 0; n < 4; ++n)
#pragma unroll
            for (int k = 0; k < 2; ++k)
                acc[2 * Q + mm][n] = __builtin_amdgcn_mfma_f32_16x16x32_bf16(
                    a[mm][k], b[n][k], acc[2 * Q + mm][n], 0, 0, 0);
    __builtin_amdgcn_s_setprio(0);
}

template <int EPI>
__global__ __launch_bounds__(512, 2) void gemm8(
    const unsigned short* __restrict__ A,
    const unsigned short* __restrict__ Bw,
    const float* __restrict__ bias0,
    const float* __restrict__ bias1,
    void* __restrict__ out0,
    void* __restrict__ out1)
{
    constexpr int NBC = (EPI == 1) ? 6 : 3;   // N / 256
    constexpr int K   = CDIM;                 // 768
    constexpr int NT  = K / 64;               // 12 K-tiles
    constexpr int ITERS = NT / 2;             // 6

    __shared__ __align__(16) char smem[131072];

    const int tid  = threadIdx.x;
    const int lane = tid & 63;
    const int w    = tid >> 6;     // wave 0..7
    const int wm   = w >> 2;       // 0..1  (M half)
    const int wn   = w & 3;        // 0..3  (N quarter)

    // bijective XCD swizzle (nwg % 8 == 0 for all grids here)
    const int nwg = gridDim.x;
    const int bid = blockIdx.x;
    const int swz = (bid & 7) * (nwg >> 3) + (bid >> 3);
    const int tcol = swz % NBC;
    const int trow = swz / NBC;
    const int brow = trow * 256;
    const int bcol = tcol * 256;

    // ds-read lane geometry (frag reads)
    const int ln15 = lane & 15, hi4 = lane >> 4;
    const int aRowByte = (wm * 128 + ln15) * 128;
    const int bRowByte = (wn * 64 + ln15) * 128;
    const int cK0 = ((hi4) ^ (ln15 & 7)) << 4;       // k-step 0 slot byte
    const int cK1 = ((4 + hi4) ^ (ln15 & 7)) << 4;   // k-step 1 slot byte

    // staging lane geometry (pre-swizzled global source, linear LDS dest)
    const int r8  = lane >> 3;           // row within 8-row chunk
    const int csw = ((lane & 7) ^ r8) << 3;  // element col offset 0..56

    auto stage = [&](int isB, int buf, int kt, int h) {
        const unsigned short* G = isB ? Bw : A;
        const int gr0 = (isB ? bcol : brow) + h * 128 + w * 16;
        char* dbase = smem + isB * 65536 + buf * 32768 + (h * 128 + w * 16) * 128;
#pragma unroll
        for (int g = 0; g < 2; ++g) {
            const unsigned short* src =
                G + (size_t)(gr0 + g * 8 + r8) * K + kt * 64 + csw;
            GLOAD_LDS16(src, dbase + g * 1024);
        }
    };
    auto lda = [&](int buf, int m, int k) -> short8v {
        return *(const short8v*)(smem + buf * 32768 + aRowByte + m * 2048 + (k ? cK1 : cK0));
    };
    auto ldb = [&](int buf, int n, int k) -> short8v {
        return *(const short8v*)(smem + 65536 + buf * 32768 + bRowByte + n * 2048 + (k ? cK1 : cK0));
    };

#define LD_A2(buf, mb) do { a[0][0] = lda(buf, (mb), 0); a[0][1] = lda(buf, (mb), 1); \
                            a[1][0] = lda(buf, (mb) + 1, 0); a[1][1] = lda(buf, (mb) + 1, 1); } while (0)
#define LD_B8(buf) do { b[0][0] = ldb(buf, 0, 0); b[0][1] = ldb(buf, 0, 1); \
                        b[1][0] = ldb(buf, 1, 0); b[1][1] = ldb(buf, 1, 1); \
                        b[2][0] = ldb(buf, 2, 0); b[2][1] = ldb(buf, 2, 1); \
                        b[3][0] = ldb(buf, 3, 0); b[3][1] = ldb(buf, 3, 1); } while (0)

    f32x4 acc[8][4];
#pragma unroll
    for (int i = 0; i < 8; ++i)
#pragma unroll
        for (int j = 0; j < 4; ++j)
            acc[i][j] = (f32x4){0.f, 0.f, 0.f, 0.f};

    // prologue: tile0 (A0,A1,B0,B1) + tile1 (B0,B1)
    stage(0, 0, 0, 0); stage(0, 0, 0, 1);
    stage(1, 0, 0, 0); stage(1, 0, 0, 1);
    stage(1, 1, 1, 0); stage(1, 1, 1, 1);
    VM4();
    SBAR();

    short8v a[2][2], b[4][2];

    for (int t = 0; t < ITERS; ++t) {
        const int o  = 2 * t + 1;
        const int e2 = 2 * t + 2;
        const int o2 = 2 * t + 3;
        const bool last = (t == ITERS - 1);

        // ---- phase 1: tile e (buf0) quad 0 ---- stage o.A h0
        LD_B8(0); LD_A2(0, 0);
        stage(0, 1, o, 0);
        SBAR();
        mfma_quad<0>(acc, a, b);
        SBAR();
        // ---- phase 2: quad 1 ---- stage o.A h1
        LD_A2(0, 2);
        stage(0, 1, o, 1);
        SBAR();
        mfma_quad<1>(acc, a, b);
        SBAR();
        // ---- phase 3: quad 2 ---- stage e2.B h0
        LD_A2(0, 4);
        if (!last) stage(1, 0, e2, 0);
        SBAR();
        mfma_quad<2>(acc, a, b);
        SBAR();
        // ---- phase 4: quad 3 ---- stage e2.B h1; counted wait
        LD_A2(0, 6);
        if (!last) stage(1, 0, e2, 1);
        SBAR();
        mfma_quad<3>(acc, a, b);
        if (last) { VM0(); } else { VM4(); }
        SBAR();
        // ---- phase 5: tile o (buf1) quad 0 ---- stage e2.A h0
        LD_B8(1); LD_A2(1, 0);
        if (!last) stage(0, 0, e2, 0);
        SBAR();
        mfma_quad<0>(acc, a, b);
        SBAR();
        // ---- phase 6: quad 1 ---- stage e2.A h1
        LD_A2(1, 2);
        if (!last) stage(0, 0, e2, 1);
        SBAR();
        mfma_quad<1>(acc, a, b);
        SBAR();
        // ---- phase 7: quad 2 ---- stage o2.B h0
        LD_A2(1, 4);
        if (!last) stage(1, 1, o2, 0);
        SBAR();
        mfma_quad<2>(acc, a, b);
        SBAR();
        // ---- phase 8: quad 3 ---- stage o2.B h1; counted wait
        LD_A2(1, 6);
        if (!last) stage(1, 1, o2, 1);
        SBAR();
        mfma_quad<3>(acc, a, b);
        if (last) { VM0(); } else { VM4(); }
        SBAR();
    }
#undef LD_A2
#undef LD_B8

    // ---------------- epilogue: per-wave LDS staging, vectorized stores
    constexpr int N = NBC * 256;
    float* ep = (float*)(void*)smem + w * (16 * 68);
    const int rr = lane >> 2;
    const int cb = (lane & 3) * 4;
#pragma unroll
    for (int m = 0; m < 8; ++m) {
#pragma unroll
        for (int n = 0; n < 4; ++n)
#pragma unroll
            for (int r = 0; r < 4; ++r)
                ep[(hi4 * 4 + r) * 68 + n * 16 + ln15] = acc[m][n][r];
#pragma unroll
        for (int q = 0; q < 4; ++q) {
            const int cc = q * 16 + cb;
            f32x4 v = *(const f32x4*)&ep[rr * 68 + cc];
            const int rg = brow + wm * 128 + m * 16 + rr;
            const int cg = bcol + wn * 64 + cc;
            if (EPI == 0) {
                float4 bb = *(const float4*)&bias0[cg];
                ushort4 ov;
                ov.x = f2b(phi_f((v[0] + bb.x) * QSCALE));
                ov.y = f2b(phi_f((v[1] + bb.y) * QSCALE));
                ov.z = f2b(phi_f((v[2] + bb.z) * QSCALE));
                ov.w = f2b(phi_f((v[3] + bb.w) * QSCALE));
                *(ushort4*)((unsigned short*)out0 + (size_t)rg * 768 + cg) = ov;
            } else if (EPI == 1) {
                if (cg < 768) {
                    float4 bb = *(const float4*)&bias0[cg];
                    ushort4 ov;
                    ov.x = f2b(phi_f(v[0] + bb.x));
                    ov.y = f2b(phi_f(v[1] + bb.y));
                    ov.z = f2b(phi_f(v[2] + bb.z));
                    ov.w = f2b(phi_f(v[3] + bb.w));
                    *(ushort4*)((unsigned short*)out0 + (size_t)rg * 768 + cg) = ov;
                } else {
                    float4 bb = *(const float4*)&bias1[cg - 768];
                    ushort4 ov;
                    ov.x = f2b(v[0] + bb.x);
                    ov.y = f2b(v[1] + bb.y);
                    ov.z = f2b(v[2] + bb.z);
                    ov.w = f2b(v[3] + bb.w);
                    *(ushort4*)((unsigned short*)out1 + (size_t)rg * 768 + (cg - 768)) = ov;
                }
            } else {
                float4 bb = *(const float4*)&bias0[cg];
                float4 ov;
                ov.x = v[0] + bb.x; ov.y = v[1] + bb.y;
                ov.z = v[2] + bb.z; ov.w = v[3] + bb.w;
                *(float4*)((float*)out0 + (size_t)rg * 768 + cg) = ov;
            }
        }
    }
}

// ---------------------------------------------------------------- KV state
#define KVCH   128
#define KVITER 2
#define NCHUNK 16   // SEQ / (KVCH*KVITER)

__global__ __launch_bounds__(256) void kv_part(
    const unsigned short* __restrict__ kphi,
    const unsigned short* __restrict__ vmat,
    float* __restrict__ part)
{
    const int bh = blockIdx.y;                // 0..47
    const int b  = bh / HEADS, h = bh % HEADS;
    const int c  = blockIdx.x;                // 0..NCHUNK-1
    __shared__ float Kl[KVCH][HDIM];
    __shared__ float Vl[KVCH][HDIM];
    const int t  = threadIdx.x;
    const int i  = t >> 2;      // kv row d, 0..63
    const int jb = t & 3;       // 16-col group

    float acc[16];
#pragma unroll
    for (int jj = 0; jj < 16; ++jj) acc[jj] = 0.f;
    float ksum = 0.f;

    for (int it = 0; it < KVITER; ++it) {
        const size_t rbase = (size_t)b * SEQ + (size_t)c * (KVCH * KVITER) + it * KVCH;
        __syncthreads();
        for (int l = 0; l < KVCH / 32; ++l) {
            int row = l * 32 + (t >> 3);
            int col = (t & 7) << 3;
            const size_t g = (rbase + row) * CDIM + h * HDIM + col;
            int4 kk = *(const int4*)(kphi + g);
            int4 vv = *(const int4*)(vmat + g);
            const unsigned short* kp = (const unsigned short*)&kk;
            const unsigned short* vp = (const unsigned short*)&vv;
#pragma unroll
            for (int q = 0; q < 8; ++q) {
                Kl[row][col + q] = b2f(kp[q]);
                Vl[row][col + q] = b2f(vp[q]);
            }
        }
        __syncthreads();
        for (int n = 0; n < KVCH; ++n) {
            float kf = Kl[n][i];
            const float4* vr = (const float4*)&Vl[n][jb * 16];
            float4 v0 = vr[0], v1 = vr[1], v2 = vr[2], v3 = vr[3];
            acc[0]  += kf * v0.x; acc[1]  += kf * v0.y; acc[2]  += kf * v0.z; acc[3]  += kf * v0.w;
            acc[4]  += kf * v1.x; acc[5]  += kf * v1.y; acc[6]  += kf * v1.z; acc[7]  += kf * v1.w;
            acc[8]  += kf * v2.x; acc[9]  += kf * v2.y; acc[10] += kf * v2.z; acc[11] += kf * v2.w;
            acc[12] += kf * v3.x; acc[13] += kf * v3.y; acc[14] += kf * v3.z; acc[15] += kf * v3.w;
            ksum += kf;
        }
    }
    float* op = part + ((size_t)c * 48 + bh) * 4160;
#pragma unroll
    for (int jj = 0; jj < 16; ++jj) op[i * 64 + jb * 16 + jj] = acc[jj];
    if (jb == 0) op[4096 + i] = ksum;
}

__global__ void kv_finalize(const float* __restrict__ part, float* __restrict__ kv) {
    int idx = blockIdx.x * 256 + threadIdx.x;
    if (idx >= 48 * 4160) return;
    float s = 0.f;
    for (int c = 0; c < NCHUNK; ++c) s += part[(size_t)c * 48 * 4160 + idx];
    kv[idx] = s;
}

// ---------------------------------------------------------------- apply
__global__ __launch_bounds__(256) void attn_apply(
    const unsigned short* __restrict__ qphi,
    const float* __restrict__ kv,
    unsigned short* __restrict__ attn)
{
    const int h  = blockIdx.y;
    const int m0 = blockIdx.x * 64;
    const int b  = m0 >> 12;
    const int bh = b * HEADS + h;
    __shared__ float kvs[HDIM][HDIM];
    __shared__ float ksums[HDIM];
    __shared__ unsigned short ql[64][HDIM];
    const int t = threadIdx.x;
    const float* kvp = kv + (size_t)bh * 4160;
#pragma unroll
    for (int it = 0; it < 4; ++it) {
        int e = it * 1024 + t * 4;
        *(float4*)&kvs[e >> 6][e & 63] = *(const float4*)&kvp[e];
    }
    if (t < 64) ksums[t] = kvp[4096 + t];
#pragma unroll
    for (int it = 0; it < 2; ++it) {
        int row = it * 32 + (t >> 3);
        int col = (t & 7) << 3;
        *(int4*)&ql[row][col] =
            *(const int4*)(qphi + (size_t)(m0 + row) * CDIM + h * HDIM + col);
    }
    __syncthreads();

    const int r  = t >> 2;
    const int jb = t & 3;
    float acc[16];
#pragma unroll
    for (int jj = 0; jj < 16; ++jj) acc[jj] = 0.f;
    float z = 0.f;
    for (int q8 = 0; q8 < 8; ++q8) {
        short8v qv = *(const short8v*)&ql[r][q8 * 8];
#pragma unroll
        for (int dd = 0; dd < 8; ++dd) {
            float qd = b2f((unsigned short)qv[dd]);
            int d = q8 * 8 + dd;
            const float4* kr = (const float4*)&kvs[d][jb * 16];
            float4 k0 = kr[0], k1 = kr[1], k2 = kr[2], k3 = kr[3];
            acc[0]  += qd * k0.x; acc[1]  += qd * k0.y; acc[2]  += qd * k0.z; acc[3]  += qd * k0.w;
            acc[4]  += qd * k1.x; acc[5]  += qd * k1.y; acc[6]  += qd * k1.z; acc[7]  += qd * k1.w;
            acc[8]  += qd * k2.x; acc[9]  += qd * k2.y; acc[10] += qd * k2.z; acc[11] += qd * k2.w;
            acc[12] += qd * k3.x; acc[13] += qd * k3.y; acc[14] += qd * k3.z; acc[15] += qd * k3.w;
            z += qd * ksums[d];
        }
    }
    const float inv = 1.f / (z + EPSV);
    unsigned short* op = attn + (size_t)(m0 + r) * CDIM + h * HDIM + jb * 16;
#pragma unroll
    for (int jj = 0; jj < 16; ++jj) op[jj] = f2b(acc[jj] * inv);
}

// ---------------------------------------------------------------- launch
extern "C" void kernel_launch(void* const* d_in, const int* in_sizes, int n_in,
                              void* d_out, int out_size, void* d_ws, size_t ws_size,
                              hipStream_t stream)
{
    const float* x_q  = (const float*)d_in[0];
    const float* x_kv = (const float*)d_in[1];
    const float* Wq   = (const float*)d_in[2];
    const float* bq   = (const float*)d_in[3];
    const float* Wk   = (const float*)d_in[4];
    const float* bk   = (const float*)d_in[5];
    const float* Wv   = (const float*)d_in[6];
    const float* bv   = (const float*)d_in[7];
    const float* Wp   = (const float*)d_in[8];
    const float* bp   = (const float*)d_in[9];
    float* out = (float*)d_out;

    char* ws = (char*)d_ws;
    size_t off = 0;
    auto alloc = [&](size_t bytes) -> char* {
        char* p = ws + off;
        off += (bytes + 255) & ~(size_t)255;
        return p;
    };
    const size_t xbytes = (size_t)MROWS * CDIM * 2;
    const size_t wbytes = (size_t)CDIM * CDIM * 2;
    unsigned short* xq16  = (unsigned short*)alloc(xbytes);
    unsigned short* xkv16 = (unsigned short*)alloc(xbytes);
    unsigned short* wk16  = (unsigned short*)alloc(wbytes);  // contiguous with wv16
    unsigned short* wv16  = (unsigned short*)alloc(wbytes);
    unsigned short* wq16  = (unsigned short*)alloc(wbytes);
    unsigned short* wp16  = (unsigned short*)alloc(wbytes);
    unsigned short* qphi  = (unsigned short*)alloc(xbytes);
    unsigned short* kphi  = (unsigned short*)alloc(xbytes);
    unsigned short* v16   = (unsigned short*)alloc(xbytes);
    float* part = (float*)alloc((size_t)NCHUNK * 48 * 4160 * 4);
    float* kvf  = (float*)alloc((size_t)48 * 4160 * 4);
    unsigned short* attn16 = xq16;   // reuse: x_q bf16 dead after Q projection

    const int n4x = MROWS * CDIM / 4;   // 3145728
    const int n4w = CDIM * CDIM / 4;    // 147456
    cvt_f32_bf16<<<n4x / 256, 256, 0, stream>>>(x_q,  xq16,  n4x);
    cvt_f32_bf16<<<n4x / 256, 256, 0, stream>>>(x_kv, xkv16, n4x);
    cvt_f32_bf16<<<n4w / 256, 256, 0, stream>>>(Wq, wq16, n4w);
    cvt_f32_bf16<<<n4w / 256, 256, 0, stream>>>(Wk, wk16, n4w);
    cvt_f32_bf16<<<n4w / 256, 256, 0, stream>>>(Wv, wv16, n4w);
    cvt_f32_bf16<<<n4w / 256, 256, 0, stream>>>(Wp, wp16, n4w);

    // Q projection: 64x3 tiles
    gemm8<0><<<192, 512, 0, stream>>>(xq16, wq16, bq, nullptr, (void*)qphi, nullptr);
    // fused K|V projection: 64x6 tiles, B = [Wk; Wv] (contiguous)
    gemm8<1><<<384, 512, 0, stream>>>(xkv16, wk16, bk, bv, (void*)kphi, (void*)v16);

    kv_part<<<dim3(NCHUNK, 48), 256, 0, stream>>>(kphi, v16, part);
    kv_finalize<<<(48 * 4160 + 255) / 256, 256, 0, stream>>>(part, kvf);
    attn_apply<<<dim3(MROWS / 64, HEADS), 256, 0, stream>>>(qphi, kvf, attn16);

    // output projection -> fp32
    gemm8<2><<<192, 512, 0, stream>>>(attn16, wp16, bp, nullptr, (void*)out, nullptr);
}

// Round 3
// 232.119 us; speedup vs baseline: 1.1071x; 1.1071x over previous
//
#include <hip/hip_runtime.h>
#include <hip/hip_bf16.h>
#include <cstdint>
#include <cstddef>

#define HD_B   4
#define SEQ    4096
#define CDIM   768
#define HEADS  12
#define HDIM   64
#define MROWS  (HD_B * SEQ)     // 16384
#define QSCALE 0.125f
#define EPSV   1e-6f

typedef __attribute__((ext_vector_type(8))) short  short8v;  // 8 x bf16
typedef __attribute__((ext_vector_type(4))) float  f32x4;

__device__ __forceinline__ unsigned short f2b(float f) {
    unsigned int u = __float_as_uint(f);
    u += 0x7FFFu + ((u >> 16) & 1u);   // RNE
    return (unsigned short)(u >> 16);
}
__device__ __forceinline__ float b2f(unsigned short b) {
    return __uint_as_float(((unsigned int)b) << 16);
}
__device__ __forceinline__ float phi_f(float x) {  // elu(x)+1
    return x > 0.f ? x + 1.f : __expf(x);
}

#define GLOAD_LDS16(g, l)                                             \
    __builtin_amdgcn_global_load_lds(                                 \
        (__attribute__((address_space(1))) void*)(void*)(g),          \
        (__attribute__((address_space(3))) void*)(l), 16, 0, 0)

// ---------------------------------------------------------------- weight cvt (all 4 in one dispatch)
__global__ void wcvt_all(const float* __restrict__ wk, const float* __restrict__ wv,
                         const float* __restrict__ wq, const float* __restrict__ wp,
                         unsigned short* __restrict__ dst) {
    const int y = blockIdx.y;
    const float* src = (y == 0) ? wk : (y == 1) ? wv : (y == 2) ? wq : wp;
    const int i = blockIdx.x * 256 + threadIdx.x;          // 0..147455 float4 groups
    float4 v = reinterpret_cast<const float4*>(src)[i];
    ushort4 o;
    o.x = f2b(v.x); o.y = f2b(v.y); o.z = f2b(v.z); o.w = f2b(v.w);
    reinterpret_cast<ushort4*>(dst + (size_t)y * (CDIM * CDIM))[i] = o;
}

// ---------------------------------------------------------------- GEMM 128x128, BK=64, swizzled LDS
// C[m,n] = sum_k A[m,k]*B[n,k]; K = 768 fixed; out row stride 768.
// EPI 0: Q  -> bf16 out0 = phi(QSCALE*(acc+bias0))
// EPI 1: KV -> bcol<768: bf16 out0 = phi(acc+bias0); else bf16 out1 = acc+bias1 (col-768)
// EPI 2: P  -> fp32 out0 = acc+bias0
// AFP32: 1 = A is fp32, reg-staged with in-kernel bf16 convert; 0 = A is bf16 (gload_lds)
template <int EPI, int AFP32>
__global__ __launch_bounds__(256) void gemm_bt(
    const void* __restrict__ Ain,
    const unsigned short* __restrict__ Bw,
    const float* __restrict__ bias0,
    const float* __restrict__ bias1,
    void* __restrict__ out0,
    void* __restrict__ out1)
{
    constexpr int K = CDIM;                  // 768
    __shared__ __align__(16) char smem[32768];
    auto As = (unsigned short (*)[64])(smem);            // 16 KB
    auto Bs = (unsigned short (*)[64])(smem + 16384);    // 16 KB

    const int tid  = threadIdx.x;
    const int lane = tid & 63;
    const int w    = tid >> 6;        // wave 0..3
    const int wr   = w >> 1;          // 0..1
    const int wc   = w & 1;           // 0..1
    const int brow = blockIdx.x * 128;
    const int bcol = blockIdx.y * 128;

    f32x4 acc[4][4];
#pragma unroll
    for (int i = 0; i < 4; ++i)
#pragma unroll
        for (int j = 0; j < 4; ++j)
            acc[i][j] = (f32x4){0.f, 0.f, 0.f, 0.f};

    // gload_lds staging geometry: 1 inst = 64 lanes x 16B = 8 rows of 128B
    const int r8 = lane >> 3;                  // row within 8-row chunk
    const int c8 = ((lane & 7) ^ r8) << 3;     // pre-swizzled col (elements)
    // fp32 reg-staging geometry: 16 lanes/row, 4 rows/inst
    const int ar = lane >> 4;                  // 0..3
    const int ac = (lane & 15) << 2;           // col (fp32 elements)
    // frag-read geometry
    const int fr  = lane & 15;
    const int hi4 = lane >> 4;

    const float* A32          = (const float*)Ain;
    const unsigned short* A16 = (const unsigned short*)Ain;

    for (int k0 = 0; k0 < K; k0 += 64) {
        // ---- stage B (4 x global_load_lds, fire-and-forget)
#pragma unroll
        for (int g = 0; g < 4; ++g) {
            const unsigned short* src =
                Bw + (size_t)(bcol + w * 32 + g * 8 + r8) * K + k0 + c8;
            GLOAD_LDS16(src, (char*)Bs + (w * 32 + g * 8) * 128);
        }
        // ---- stage A
        if (AFP32) {
#pragma unroll
            for (int j = 0; j < 8; ++j) {
                const int row = w * 32 + j * 4 + ar;
                float4 f = *(const float4*)(A32 + (size_t)(brow + row) * K + k0 + ac);
                unsigned int p0, p1;
                asm("v_cvt_pk_bf16_f32 %0, %1, %2" : "=v"(p0) : "v"(f.x), "v"(f.y));
                asm("v_cvt_pk_bf16_f32 %0, %1, %2" : "=v"(p1) : "v"(f.z), "v"(f.w));
                const int off = row * 128 + (((ac << 1)) ^ ((row & 7) << 4));
                uint2 pk; pk.x = p0; pk.y = p1;
                *(uint2*)((char*)As + off) = pk;
            }
        } else {
#pragma unroll
            for (int g = 0; g < 4; ++g) {
                const unsigned short* src =
                    A16 + (size_t)(brow + w * 32 + g * 8 + r8) * K + k0 + c8;
                GLOAD_LDS16(src, (char*)As + (w * 32 + g * 8) * 128);
            }
        }
        __syncthreads();   // drains vmcnt + lgkm

        // ---- frag reads (swizzled)
        short8v a[4][2], b[4][2];
#pragma unroll
        for (int i = 0; i < 4; ++i) {
            const int row = wr * 64 + i * 16 + fr;
#pragma unroll
            for (int ks = 0; ks < 2; ++ks) {
                const int off = row * 128 + ((((ks << 2) + hi4) ^ (row & 7)) << 4);
                a[i][ks] = *(const short8v*)((const char*)As + off);
            }
        }
#pragma unroll
        for (int j = 0; j < 4; ++j) {
            const int row = wc * 64 + j * 16 + fr;
#pragma unroll
            for (int ks = 0; ks < 2; ++ks) {
                const int off = row * 128 + ((((ks << 2) + hi4) ^ (row & 7)) << 4);
                b[j][ks] = *(const short8v*)((const char*)Bs + off);
            }
        }
        // ---- 32 MFMA
#pragma unroll
        for (int i = 0; i < 4; ++i)
#pragma unroll
            for (int j = 0; j < 4; ++j) {
                acc[i][j] = __builtin_amdgcn_mfma_f32_16x16x32_bf16(
                    a[i][0], b[j][0], acc[i][j], 0, 0, 0);
                acc[i][j] = __builtin_amdgcn_mfma_f32_16x16x32_bf16(
                    a[i][1], b[j][1], acc[i][j], 0, 0, 0);
            }
        __syncthreads();
    }

    // ---------------- epilogue: wave-private LDS transpose, vectorized stores
    float* ep = (float*)smem + w * (16 * 68);   // 4352 B per wave
    const int rr = lane >> 2;
    const int cb = (lane & 3) * 4;

    const bool isV = (EPI == 1) && (bcol >= 768);
    const float* bptr = (EPI == 1 && isV) ? (bias1 + (bcol - 768)) : (bias0 + bcol);
    const int colbase = (isV ? bcol - 768 : bcol) + wc * 64;
    unsigned short* o16 = (unsigned short*)(isV ? out1 : out0);
    float* o32 = (float*)out0;

    float4 bb[4];
#pragma unroll
    for (int q = 0; q < 4; ++q)
        bb[q] = *(const float4*)&bptr[wc * 64 + q * 16 + cb];

#pragma unroll
    for (int i = 0; i < 4; ++i) {
#pragma unroll
        for (int j = 0; j < 4; ++j)
#pragma unroll
            for (int r = 0; r < 4; ++r)
                ep[(hi4 * 4 + r) * 68 + j * 16 + fr] = acc[i][j][r];
#pragma unroll
        for (int q = 0; q < 4; ++q) {
            const int cc = q * 16 + cb;
            f32x4 v = *(const f32x4*)&ep[rr * 68 + cc];
            const int rg = brow + wr * 64 + i * 16 + rr;
            const int cg = colbase + cc;
            const float4 bq = bb[q];
            if (EPI == 0) {
                ushort4 ov;
                ov.x = f2b(phi_f((v[0] + bq.x) * QSCALE));
                ov.y = f2b(phi_f((v[1] + bq.y) * QSCALE));
                ov.z = f2b(phi_f((v[2] + bq.z) * QSCALE));
                ov.w = f2b(phi_f((v[3] + bq.w) * QSCALE));
                *(ushort4*)(o16 + (size_t)rg * 768 + cg) = ov;
            } else if (EPI == 1) {
                ushort4 ov;
                if (!isV) {
                    ov.x = f2b(phi_f(v[0] + bq.x));
                    ov.y = f2b(phi_f(v[1] + bq.y));
                    ov.z = f2b(phi_f(v[2] + bq.z));
                    ov.w = f2b(phi_f(v[3] + bq.w));
                } else {
                    ov.x = f2b(v[0] + bq.x);
                    ov.y = f2b(v[1] + bq.y);
                    ov.z = f2b(v[2] + bq.z);
                    ov.w = f2b(v[3] + bq.w);
                }
                *(ushort4*)(o16 + (size_t)rg * 768 + cg) = ov;
            } else {
                float4 ov;
                ov.x = v[0] + bq.x; ov.y = v[1] + bq.y;
                ov.z = v[2] + bq.z; ov.w = v[3] + bq.w;
                *(float4*)(o32 + (size_t)rg * 768 + cg) = ov;
            }
        }
    }
}

// ---------------------------------------------------------------- KV state
#define KVCH   128
#define KVITER 2
#define NCHUNK 16   // SEQ / (KVCH*KVITER)

__global__ __launch_bounds__(256) void kv_part(
    const unsigned short* __restrict__ kphi,
    const unsigned short* __restrict__ vmat,
    float* __restrict__ part)
{
    const int bh = blockIdx.y;                // 0..47
    const int b  = bh / HEADS, h = bh % HEADS;
    const int c  = blockIdx.x;                // 0..NCHUNK-1
    __shared__ float Kl[KVCH][HDIM];
    __shared__ float Vl[KVCH][HDIM];
    const int t  = threadIdx.x;
    const int i  = t >> 2;      // kv row d, 0..63
    const int jb = t & 3;       // 16-col group

    float acc[16];
#pragma unroll
    for (int jj = 0; jj < 16; ++jj) acc[jj] = 0.f;
    float ksum = 0.f;

    for (int it = 0; it < KVITER; ++it) {
        const size_t rbase = (size_t)b * SEQ + (size_t)c * (KVCH * KVITER) + it * KVCH;
        __syncthreads();
        for (int l = 0; l < KVCH / 32; ++l) {
            int row = l * 32 + (t >> 3);
            int col = (t & 7) << 3;
            const size_t g = (rbase + row) * CDIM + h * HDIM + col;
            int4 kk = *(const int4*)(kphi + g);
            int4 vv = *(const int4*)(vmat + g);
            const unsigned short* kp = (const unsigned short*)&kk;
            const unsigned short* vp = (const unsigned short*)&vv;
#pragma unroll
            for (int q = 0; q < 8; ++q) {
                Kl[row][col + q] = b2f(kp[q]);
                Vl[row][col + q] = b2f(vp[q]);
            }
        }
        __syncthreads();
        for (int n = 0; n < KVCH; ++n) {
            float kf = Kl[n][i];
            const float4* vr = (const float4*)&Vl[n][jb * 16];
            float4 v0 = vr[0], v1 = vr[1], v2 = vr[2], v3 = vr[3];
            acc[0]  += kf * v0.x; acc[1]  += kf * v0.y; acc[2]  += kf * v0.z; acc[3]  += kf * v0.w;
            acc[4]  += kf * v1.x; acc[5]  += kf * v1.y; acc[6]  += kf * v1.z; acc[7]  += kf * v1.w;
            acc[8]  += kf * v2.x; acc[9]  += kf * v2.y; acc[10] += kf * v2.z; acc[11] += kf * v2.w;
            acc[12] += kf * v3.x; acc[13] += kf * v3.y; acc[14] += kf * v3.z; acc[15] += kf * v3.w;
            ksum += kf;
        }
    }
    float* op = part + ((size_t)c * 48 + bh) * 4160;
#pragma unroll
    for (int jj = 0; jj < 16; ++jj) op[i * 64 + jb * 16 + jj] = acc[jj];
    if (jb == 0) op[4096 + i] = ksum;
}

__global__ void kv_finalize(const float* __restrict__ part, float* __restrict__ kv) {
    int idx = blockIdx.x * 256 + threadIdx.x;
    if (idx >= 48 * 4160) return;
    float s = 0.f;
    for (int c = 0; c < NCHUNK; ++c) s += part[(size_t)c * 48 * 4160 + idx];
    kv[idx] = s;
}

// ---------------------------------------------------------------- apply
__global__ __launch_bounds__(256) void attn_apply(
    const unsigned short* __restrict__ qphi,
    const float* __restrict__ kv,
    unsigned short* __restrict__ attn)
{
    const int h  = blockIdx.y;
    const int m0 = blockIdx.x * 64;
    const int b  = m0 >> 12;
    const int bh = b * HEADS + h;
    __shared__ float kvs[HDIM][HDIM];
    __shared__ float ksums[HDIM];
    __shared__ unsigned short ql[64][HDIM];
    const int t = threadIdx.x;
    const float* kvp = kv + (size_t)bh * 4160;
#pragma unroll
    for (int it = 0; it < 4; ++it) {
        int e = it * 1024 + t * 4;
        *(float4*)&kvs[e >> 6][e & 63] = *(const float4*)&kvp[e];
    }
    if (t < 64) ksums[t] = kvp[4096 + t];
#pragma unroll
    for (int it = 0; it < 2; ++it) {
        int row = it * 32 + (t >> 3);
        int col = (t & 7) << 3;
        *(int4*)&ql[row][col] =
            *(const int4*)(qphi + (size_t)(m0 + row) * CDIM + h * HDIM + col);
    }
    __syncthreads();

    const int r  = t >> 2;
    const int jb = t & 3;
    float acc[16];
#pragma unroll
    for (int jj = 0; jj < 16; ++jj) acc[jj] = 0.f;
    float z = 0.f;
    for (int q8 = 0; q8 < 8; ++q8) {
        short8v qv = *(const short8v*)&ql[r][q8 * 8];
#pragma unroll
        for (int dd = 0; dd < 8; ++dd) {
            float qd = b2f((unsigned short)qv[dd]);
            int d = q8 * 8 + dd;
            const float4* kr = (const float4*)&kvs[d][jb * 16];
            float4 k0 = kr[0], k1 = kr[1], k2 = kr[2], k3 = kr[3];
            acc[0]  += qd * k0.x; acc[1]  += qd * k0.y; acc[2]  += qd * k0.z; acc[3]  += qd * k0.w;
            acc[4]  += qd * k1.x; acc[5]  += qd * k1.y; acc[6]  += qd * k1.z; acc[7]  += qd * k1.w;
            acc[8]  += qd * k2.x; acc[9]  += qd * k2.y; acc[10] += qd * k2.z; acc[11] += qd * k2.w;
            acc[12] += qd * k3.x; acc[13] += qd * k3.y; acc[14] += qd * k3.z; acc[15] += qd * k3.w;
            z += qd * ksums[d];
        }
    }
    const float inv = 1.f / (z + EPSV);
    unsigned short* op = attn + (size_t)(m0 + r) * CDIM + h * HDIM + jb * 16;
#pragma unroll
    for (int jj = 0; jj < 16; ++jj) op[jj] = f2b(acc[jj] * inv);
}

// ---------------------------------------------------------------- launch
extern "C" void kernel_launch(void* const* d_in, const int* in_sizes, int n_in,
                              void* d_out, int out_size, void* d_ws, size_t ws_size,
                              hipStream_t stream)
{
    const float* x_q  = (const float*)d_in[0];
    const float* x_kv = (const float*)d_in[1];
    const float* Wq   = (const float*)d_in[2];
    const float* bq   = (const float*)d_in[3];
    const float* Wk   = (const float*)d_in[4];
    const float* bk   = (const float*)d_in[5];
    const float* Wv   = (const float*)d_in[6];
    const float* bv   = (const float*)d_in[7];
    const float* Wp   = (const float*)d_in[8];
    const float* bp   = (const float*)d_in[9];
    float* out = (float*)d_out;

    char* ws = (char*)d_ws;
    size_t off = 0;
    auto alloc = [&](size_t bytes) -> char* {
        char* p = ws + off;
        off += (bytes + 255) & ~(size_t)255;
        return p;
    };
    const size_t xbytes = (size_t)MROWS * CDIM * 2;
    const size_t wbytes = (size_t)CDIM * CDIM * 2;
    // weights contiguous in order [Wk, Wv, Wq, Wp]
    unsigned short* w16   = (unsigned short*)alloc(4 * wbytes);
    unsigned short* wk16  = w16;
    unsigned short* wq16  = w16 + 2 * (CDIM * CDIM);
    unsigned short* wp16  = w16 + 3 * (CDIM * CDIM);
    unsigned short* qphi  = (unsigned short*)alloc(xbytes);
    unsigned short* kphi  = (unsigned short*)alloc(xbytes);
    unsigned short* v16   = (unsigned short*)alloc(xbytes);
    unsigned short* attn16 = (unsigned short*)alloc(xbytes);
    float* part = (float*)alloc((size_t)NCHUNK * 48 * 4160 * 4);
    float* kvf  = (float*)alloc((size_t)48 * 4160 * 4);

    wcvt_all<<<dim3(576, 4), 256, 0, stream>>>(Wk, Wv, Wq, Wp, w16);

    // Q projection (fp32 A): grid (M/128, 768/128)
    gemm_bt<0, 1><<<dim3(128, 6), 256, 0, stream>>>(
        (const void*)x_q, wq16, bq, nullptr, (void*)qphi, nullptr);
    // fused K|V projection (fp32 A), B = [Wk; Wv] contiguous: grid (128, 12)
    gemm_bt<1, 1><<<dim3(128, 12), 256, 0, stream>>>(
        (const void*)x_kv, wk16, bk, bv, (void*)kphi, (void*)v16);

    kv_part<<<dim3(NCHUNK, 48), 256, 0, stream>>>(kphi, v16, part);
    kv_finalize<<<(48 * 4160 + 255) / 256, 256, 0, stream>>>(part, kvf);
    attn_apply<<<dim3(MROWS / 64, HEADS), 256, 0, stream>>>(qphi, kvf, attn16);

    // output projection (bf16 A) -> fp32
    gemm_bt<2, 0><<<dim3(128, 6), 256, 0, stream>>>(
        (const void*)attn16, wp16, bp, nullptr, (void*)out, nullptr);
}

// Round 4
// 224.400 us; speedup vs baseline: 1.1452x; 1.0344x over previous
//
#include <hip/hip_runtime.h>
#include <hip/hip_bf16.h>
#include <cstdint>
#include <cstddef>

#define HD_B   4
#define SEQ    4096
#define CDIM   768
#define HEADS  12
#define HDIM   64
#define MROWS  (HD_B * SEQ)     // 16384
#define QSCALE 0.125f
#define EPSV   1e-6f

typedef __attribute__((ext_vector_type(8))) short  short8v;  // 8 x bf16
typedef __attribute__((ext_vector_type(4))) float  f32x4;

__device__ __forceinline__ unsigned short f2b(float f) {
    unsigned int u = __float_as_uint(f);
    u += 0x7FFFu + ((u >> 16) & 1u);   // RNE
    return (unsigned short)(u >> 16);
}
__device__ __forceinline__ float b2f(unsigned short b) {
    return __uint_as_float(((unsigned int)b) << 16);
}
__device__ __forceinline__ float phi_f(float x) {  // elu(x)+1
    return x > 0.f ? x + 1.f : __expf(x);
}

#define GLOAD_LDS16(g, l)                                             \
    __builtin_amdgcn_global_load_lds(                                 \
        (__attribute__((address_space(1))) void*)(void*)(g),          \
        (__attribute__((address_space(3))) void*)(l), 16, 0, 0)

// ---------------------------------------------------------------- weight cvt
// dst contiguous: [Wq | Wk | Wv | Wp]
__global__ void wcvt_all(const float* __restrict__ wq, const float* __restrict__ wk,
                         const float* __restrict__ wv, const float* __restrict__ wp,
                         unsigned short* __restrict__ dst) {
    const int y = blockIdx.y;
    const float* src = (y == 0) ? wq : (y == 1) ? wk : (y == 2) ? wv : wp;
    const int i = blockIdx.x * 256 + threadIdx.x;
    float4 v = reinterpret_cast<const float4*>(src)[i];
    ushort4 o;
    o.x = f2b(v.x); o.y = f2b(v.y); o.z = f2b(v.z); o.w = f2b(v.w);
    reinterpret_cast<ushort4*>(dst + (size_t)y * (CDIM * CDIM))[i] = o;
}

// ---------------------------------------------------------------- pipelined GEMM
// 128x128 tile, BK=64, double-buffered LDS (64 KB), 2-phase pipeline.
// KIND 0: fused Q|K|V projections. Grid 2304 blocks = 18 col-panels x 128 row-panels.
//         colp/6 = mode: 0 -> A=x_q, B=Wq, out=phi(QSCALE*(acc+bq)) -> qphi
//                        1 -> A=x_kv,B=Wk, out=phi(acc+bk)          -> kphi
//                        2 -> A=x_kv,B=Wv, out=acc+bv               -> v16
//         A is fp32, reg-staged with cvt_pk + swizzled ds_write (T14 split).
// KIND 1: output projection. Grid 768 blocks = 6 x 128. A bf16 (gload_lds), out fp32.
template <int KIND>
__global__ __launch_bounds__(256) void gemm_pipe(
    const float* __restrict__ Aq,
    const float* __restrict__ Akv,
    const unsigned short* __restrict__ Abf,
    const unsigned short* __restrict__ Wb,
    const float* __restrict__ b0,
    const float* __restrict__ b1,
    const float* __restrict__ b2,
    unsigned short* __restrict__ out_q,
    unsigned short* __restrict__ out_k,
    unsigned short* __restrict__ out_v,
    float* __restrict__ out_f)
{
    constexpr int K  = CDIM;                   // 768
    constexpr int NC = (KIND == 0) ? 18 : 6;
    constexpr int T  = NC * 128;               // 2304 / 768
    constexpr int NT = K / 64;                 // 12 K-steps

    __shared__ __align__(16) char smem[65536]; // As0|As1|Bs0|Bs1, 16 KB each

    const int tid  = threadIdx.x;
    const int lane = tid & 63;
    const int w    = tid >> 6;
    const int wr   = w >> 1, wc = w & 1;

    // bijective XCD swizzle, cols-fast within each XCD's row band
    const int bid  = blockIdx.x;
    const int s    = (bid & 7) * (T >> 3) + (bid >> 3);
    const int colp = s % NC;
    const int rowp = s / NC;
    const int brow = rowp * 128;
    const int mode = (KIND == 0) ? (colp / 6) : 3;
    const int bcol = (KIND == 0) ? (colp % 6) * 128 : colp * 128;

    const float* A32 = (KIND == 0) ? (mode == 0 ? Aq : Akv) : nullptr;
    const unsigned short* Bp = Wb + ((KIND == 0) ? (size_t)mode * (K * K) : 0);

    // staging geometry
    const int r8  = lane >> 3;
    const int c8  = ((lane & 7) ^ r8) << 3;    // pre-swizzled col (elements)
    const int ar  = lane >> 4;                 // fp32 stage: 4 rows/inst
    const int ac  = (lane & 15) << 2;          // fp32 stage: col (elements)
    // frag-read geometry
    const int fr  = lane & 15;
    const int hi4 = lane >> 4;

    f32x4 acc[4][4];
#pragma unroll
    for (int i = 0; i < 4; ++i)
#pragma unroll
        for (int j = 0; j < 4; ++j)
            acc[i][j] = (f32x4){0.f, 0.f, 0.f, 0.f};

    auto stageB = [&](int buf, int k0) {
        char* dst = smem + 32768 + buf * 16384;
#pragma unroll
        for (int g = 0; g < 4; ++g) {
            const unsigned short* src =
                Bp + (size_t)(bcol + w * 32 + g * 8 + r8) * K + k0 + c8;
            GLOAD_LDS16(src, dst + (w * 32 + g * 8) * 128);
        }
    };
    auto stageA16 = [&](int buf, int k0) {
        char* dst = smem + buf * 16384;
#pragma unroll
        for (int g = 0; g < 4; ++g) {
            const unsigned short* src =
                Abf + (size_t)(brow + w * 32 + g * 8 + r8) * K + k0 + c8;
            GLOAD_LDS16(src, dst + (w * 32 + g * 8) * 128);
        }
    };
    auto loadA32 = [&](int k0, float4* f) {
#pragma unroll
        for (int j = 0; j < 8; ++j) {
            const int row = w * 32 + j * 4 + ar;
            f[j] = *(const float4*)(A32 + (size_t)(brow + row) * K + k0 + ac);
        }
    };
    auto writeA32 = [&](int buf, const float4* f) {
        char* dst = smem + buf * 16384;
#pragma unroll
        for (int j = 0; j < 8; ++j) {
            const int row = w * 32 + j * 4 + ar;
            unsigned int p0, p1;
            asm("v_cvt_pk_bf16_f32 %0, %1, %2" : "=v"(p0) : "v"(f[j].x), "v"(f[j].y));
            asm("v_cvt_pk_bf16_f32 %0, %1, %2" : "=v"(p1) : "v"(f[j].z), "v"(f[j].w));
            uint2 pk; pk.x = p0; pk.y = p1;
            *(uint2*)(dst + row * 128 + ((ac << 1) ^ ((row & 7) << 4))) = pk;
        }
    };
    auto compute = [&](int buf) {
        const char* Ab = smem + buf * 16384;
        const char* Bb = smem + 32768 + buf * 16384;
        short8v a[4][2];
#pragma unroll
        for (int i = 0; i < 4; ++i) {
            const int row = wr * 64 + i * 16 + fr;
#pragma unroll
            for (int ks = 0; ks < 2; ++ks)
                a[i][ks] = *(const short8v*)(Ab + row * 128 +
                              ((((ks << 2) + hi4) ^ (row & 7)) << 4));
        }
#pragma unroll
        for (int j = 0; j < 4; ++j) {
            const int row = wc * 64 + j * 16 + fr;
            short8v bb0 = *(const short8v*)(Bb + row * 128 + ((hi4 ^ (row & 7)) << 4));
            short8v bb1 = *(const short8v*)(Bb + row * 128 + (((4 + hi4) ^ (row & 7)) << 4));
#pragma unroll
            for (int i = 0; i < 4; ++i) {
                acc[i][j] = __builtin_amdgcn_mfma_f32_16x16x32_bf16(a[i][0], bb0, acc[i][j], 0, 0, 0);
                acc[i][j] = __builtin_amdgcn_mfma_f32_16x16x32_bf16(a[i][1], bb1, acc[i][j], 0, 0, 0);
            }
        }
    };

    if (KIND == 0) {
        float4 fA[8];
        stageB(0, 0);
        loadA32(0, fA);
        asm volatile("s_waitcnt vmcnt(0)" ::: "memory");
        writeA32(0, fA);
        __syncthreads();
        for (int t = 0; t < NT; ++t) {
            const int cur = t & 1, nxt = cur ^ 1;
            if (t < NT - 1) { stageB(nxt, (t + 1) * 64); loadA32((t + 1) * 64, fA); }
            __builtin_amdgcn_sched_barrier(0);
            compute(cur);
            if (t < NT - 1) {
                asm volatile("s_waitcnt vmcnt(0)" ::: "memory");
                writeA32(nxt, fA);
                __syncthreads();
            }
        }
    } else {
        stageB(0, 0);
        stageA16(0, 0);
        __syncthreads();
        for (int t = 0; t < NT; ++t) {
            const int cur = t & 1, nxt = cur ^ 1;
            if (t < NT - 1) { stageB(nxt, (t + 1) * 64); stageA16(nxt, (t + 1) * 64); }
            __builtin_amdgcn_sched_barrier(0);
            compute(cur);
            if (t < NT - 1) __syncthreads();
        }
    }
    __syncthreads();   // all waves done with LDS buffers -> reuse for epilogue

    // ---------------- epilogue: wave-private LDS transpose, vectorized stores
    float* ep = (float*)(void*)smem + w * (16 * 68);
    const int rr = lane >> 2;
    const int cb = (lane & 3) * 4;
    const float* bptr = (KIND == 1) ? b0 : (mode == 0 ? b0 : (mode == 1 ? b1 : b2));
    unsigned short* o16 = (KIND == 0)
        ? (mode == 0 ? out_q : (mode == 1 ? out_k : out_v)) : nullptr;

    float4 bb[4];
#pragma unroll
    for (int q = 0; q < 4; ++q)
        bb[q] = *(const float4*)&bptr[bcol + wc * 64 + q * 16 + cb];

#pragma unroll
    for (int i = 0; i < 4; ++i) {
#pragma unroll
        for (int j = 0; j < 4; ++j)
#pragma unroll
            for (int r = 0; r < 4; ++r)
                ep[(hi4 * 4 + r) * 68 + j * 16 + fr] = acc[i][j][r];
#pragma unroll
        for (int q = 0; q < 4; ++q) {
            const int cc = q * 16 + cb;
            f32x4 v = *(const f32x4*)&ep[rr * 68 + cc];
            const int rg = brow + wr * 64 + i * 16 + rr;
            const int cg = bcol + wc * 64 + cc;
            const float4 bq = bb[q];
            if (KIND == 1) {
                float4 ov;
                ov.x = v[0] + bq.x; ov.y = v[1] + bq.y;
                ov.z = v[2] + bq.z; ov.w = v[3] + bq.w;
                *(float4*)(out_f + (size_t)rg * 768 + cg) = ov;
            } else {
                ushort4 ov;
                if (mode == 0) {
                    ov.x = f2b(phi_f((v[0] + bq.x) * QSCALE));
                    ov.y = f2b(phi_f((v[1] + bq.y) * QSCALE));
                    ov.z = f2b(phi_f((v[2] + bq.z) * QSCALE));
                    ov.w = f2b(phi_f((v[3] + bq.w) * QSCALE));
                } else if (mode == 1) {
                    ov.x = f2b(phi_f(v[0] + bq.x));
                    ov.y = f2b(phi_f(v[1] + bq.y));
                    ov.z = f2b(phi_f(v[2] + bq.z));
                    ov.w = f2b(phi_f(v[3] + bq.w));
                } else {
                    ov.x = f2b(v[0] + bq.x);
                    ov.y = f2b(v[1] + bq.y);
                    ov.z = f2b(v[2] + bq.z);
                    ov.w = f2b(v[3] + bq.w);
                }
                *(ushort4*)(o16 + (size_t)rg * 768 + cg) = ov;
            }
        }
    }
}

// ---------------------------------------------------------------- KV state
#define KVCH   128
#define KVITER 2
#define NCHUNK 16   // SEQ / (KVCH*KVITER)

__global__ __launch_bounds__(256) void kv_part(
    const unsigned short* __restrict__ kphi,
    const unsigned short* __restrict__ vmat,
    float* __restrict__ part)
{
    const int bh = blockIdx.y;
    const int b  = bh / HEADS, h = bh % HEADS;
    const int c  = blockIdx.x;
    __shared__ float Kl[KVCH][HDIM];
    __shared__ float Vl[KVCH][HDIM];
    const int t  = threadIdx.x;
    const int i  = t >> 2;
    const int jb = t & 3;

    float acc[16];
#pragma unroll
    for (int jj = 0; jj < 16; ++jj) acc[jj] = 0.f;
    float ksum = 0.f;

    for (int it = 0; it < KVITER; ++it) {
        const size_t rbase = (size_t)b * SEQ + (size_t)c * (KVCH * KVITER) + it * KVCH;
        __syncthreads();
        for (int l = 0; l < KVCH / 32; ++l) {
            int row = l * 32 + (t >> 3);
            int col = (t & 7) << 3;
            const size_t g = (rbase + row) * CDIM + h * HDIM + col;
            int4 kk = *(const int4*)(kphi + g);
            int4 vv = *(const int4*)(vmat + g);
            const unsigned short* kp = (const unsigned short*)&kk;
            const unsigned short* vp = (const unsigned short*)&vv;
#pragma unroll
            for (int q = 0; q < 8; ++q) {
                Kl[row][col + q] = b2f(kp[q]);
                Vl[row][col + q] = b2f(vp[q]);
            }
        }
        __syncthreads();
        for (int n = 0; n < KVCH; ++n) {
            float kf = Kl[n][i];
            const float4* vr = (const float4*)&Vl[n][jb * 16];
            float4 v0 = vr[0], v1 = vr[1], v2 = vr[2], v3 = vr[3];
            acc[0]  += kf * v0.x; acc[1]  += kf * v0.y; acc[2]  += kf * v0.z; acc[3]  += kf * v0.w;
            acc[4]  += kf * v1.x; acc[5]  += kf * v1.y; acc[6]  += kf * v1.z; acc[7]  += kf * v1.w;
            acc[8]  += kf * v2.x; acc[9]  += kf * v2.y; acc[10] += kf * v2.z; acc[11] += kf * v2.w;
            acc[12] += kf * v3.x; acc[13] += kf * v3.y; acc[14] += kf * v3.z; acc[15] += kf * v3.w;
            ksum += kf;
        }
    }
    float* op = part + ((size_t)c * 48 + bh) * 4160;
#pragma unroll
    for (int jj = 0; jj < 16; ++jj) op[i * 64 + jb * 16 + jj] = acc[jj];
    if (jb == 0) op[4096 + i] = ksum;
}

__global__ void kv_finalize(const float* __restrict__ part, float* __restrict__ kv) {
    int idx = blockIdx.x * 256 + threadIdx.x;
    if (idx >= 48 * 4160) return;
    float s = 0.f;
    for (int c = 0; c < NCHUNK; ++c) s += part[(size_t)c * 48 * 4160 + idx];
    kv[idx] = s;
}

// ---------------------------------------------------------------- apply
__global__ __launch_bounds__(256) void attn_apply(
    const unsigned short* __restrict__ qphi,
    const float* __restrict__ kv,
    unsigned short* __restrict__ attn)
{
    const int h  = blockIdx.y;
    const int m0 = blockIdx.x * 64;
    const int b  = m0 >> 12;
    const int bh = b * HEADS + h;
    __shared__ float kvs[HDIM][HDIM];
    __shared__ float ksums[HDIM];
    __shared__ unsigned short ql[64][HDIM];
    const int t = threadIdx.x;
    const float* kvp = kv + (size_t)bh * 4160;
#pragma unroll
    for (int it = 0; it < 4; ++it) {
        int e = it * 1024 + t * 4;
        *(float4*)&kvs[e >> 6][e & 63] = *(const float4*)&kvp[e];
    }
    if (t < 64) ksums[t] = kvp[4096 + t];
#pragma unroll
    for (int it = 0; it < 2; ++it) {
        int row = it * 32 + (t >> 3);
        int col = (t & 7) << 3;
        *(int4*)&ql[row][col] =
            *(const int4*)(qphi + (size_t)(m0 + row) * CDIM + h * HDIM + col);
    }
    __syncthreads();

    const int r  = t >> 2;
    const int jb = t & 3;
    float acc[16];
#pragma unroll
    for (int jj = 0; jj < 16; ++jj) acc[jj] = 0.f;
    float z = 0.f;
    for (int q8 = 0; q8 < 8; ++q8) {
        short8v qv = *(const short8v*)&ql[r][q8 * 8];
#pragma unroll
        for (int dd = 0; dd < 8; ++dd) {
            float qd = b2f((unsigned short)qv[dd]);
            int d = q8 * 8 + dd;
            const float4* kr = (const float4*)&kvs[d][jb * 16];
            float4 k0 = kr[0], k1 = kr[1], k2 = kr[2], k3 = kr[3];
            acc[0]  += qd * k0.x; acc[1]  += qd * k0.y; acc[2]  += qd * k0.z; acc[3]  += qd * k0.w;
            acc[4]  += qd * k1.x; acc[5]  += qd * k1.y; acc[6]  += qd * k1.z; acc[7]  += qd * k1.w;
            acc[8]  += qd * k2.x; acc[9]  += qd * k2.y; acc[10] += qd * k2.z; acc[11] += qd * k2.w;
            acc[12] += qd * k3.x; acc[13] += qd * k3.y; acc[14] += qd * k3.z; acc[15] += qd * k3.w;
            z += qd * ksums[d];
        }
    }
    const float inv = 1.f / (z + EPSV);
    unsigned short* op = attn + (size_t)(m0 + r) * CDIM + h * HDIM + jb * 16;
#pragma unroll
    for (int jj = 0; jj < 16; ++jj) op[jj] = f2b(acc[jj] * inv);
}

// ---------------------------------------------------------------- launch
extern "C" void kernel_launch(void* const* d_in, const int* in_sizes, int n_in,
                              void* d_out, int out_size, void* d_ws, size_t ws_size,
                              hipStream_t stream)
{
    const float* x_q  = (const float*)d_in[0];
    const float* x_kv = (const float*)d_in[1];
    const float* Wq   = (const float*)d_in[2];
    const float* bq   = (const float*)d_in[3];
    const float* Wk   = (const float*)d_in[4];
    const float* bk   = (const float*)d_in[5];
    const float* Wv   = (const float*)d_in[6];
    const float* bv   = (const float*)d_in[7];
    const float* Wp   = (const float*)d_in[8];
    const float* bp   = (const float*)d_in[9];
    float* out = (float*)d_out;

    char* ws = (char*)d_ws;
    size_t off = 0;
    auto alloc = [&](size_t bytes) -> char* {
        char* p = ws + off;
        off += (bytes + 255) & ~(size_t)255;
        return p;
    };
    const size_t xbytes = (size_t)MROWS * CDIM * 2;
    const size_t wbytes = (size_t)CDIM * CDIM * 2;
    // weights contiguous: [Wq, Wk, Wv, Wp]
    unsigned short* w16    = (unsigned short*)alloc(4 * wbytes);
    unsigned short* wp16   = w16 + 3 * (CDIM * CDIM);
    unsigned short* qphi   = (unsigned short*)alloc(xbytes);
    unsigned short* kphi   = (unsigned short*)alloc(xbytes);
    unsigned short* v16    = (unsigned short*)alloc(xbytes);
    unsigned short* attn16 = (unsigned short*)alloc(xbytes);
    float* part = (float*)alloc((size_t)NCHUNK * 48 * 4160 * 4);
    float* kvf  = (float*)alloc((size_t)48 * 4160 * 4);

    wcvt_all<<<dim3(576, 4), 256, 0, stream>>>(Wq, Wk, Wv, Wp, w16);

    // fused Q|K|V projections (fp32 A): 2304 blocks
    gemm_pipe<0><<<2304, 256, 0, stream>>>(
        x_q, x_kv, nullptr, w16, bq, bk, bv, qphi, kphi, v16, nullptr);

    kv_part<<<dim3(NCHUNK, 48), 256, 0, stream>>>(kphi, v16, part);
    kv_finalize<<<(48 * 4160 + 255) / 256, 256, 0, stream>>>(part, kvf);
    attn_apply<<<dim3(MROWS / 64, HEADS), 256, 0, stream>>>(qphi, kvf, attn16);

    // output projection (bf16 A) -> fp32: 768 blocks
    gemm_pipe<1><<<768, 256, 0, stream>>>(
        nullptr, nullptr, attn16, wp16, bp, nullptr, nullptr,
        nullptr, nullptr, nullptr, out);
}